// Round 1
// baseline (3822.467 us; speedup 1.0000x reference)
//
#include <hip/hip_runtime.h>
#include <hip/hip_bf16.h>

#define E_EDGES 800000
#define NN 50000
#define BN_EPS 1e-5f

// ---------------------------------------------------------------------------
// Layer 0: h = concat(x[dst], x[src]) @ W0   (bias b0 cancels under BN)
// thread = 1 edge, 64 fp32 accumulators, W0 (128x64, 32KB) in LDS.
// Inner loop: per 4 k's: 1 gathered float4 of x + 16 ds_read_b128 (broadcast)
// + 64 v_fma. Also counts[dst] histogram (needed for scatter-mean).
// ---------------------------------------------------------------------------
__global__ __launch_bounds__(256) void k_gemm0(
    const float* __restrict__ x, const int* __restrict__ ei,
    const float* __restrict__ W0, float* __restrict__ t,
    float* __restrict__ counts)
{
    __shared__ float wlds[128 * 64];
    {
        float4* wv = (float4*)wlds;
        const float4* w4 = (const float4*)W0;
        for (int i = threadIdx.x; i < 128 * 16; i += 256) wv[i] = w4[i];
    }
    __syncthreads();

    const int e   = blockIdx.x * 256 + threadIdx.x;  // grid = E/256 exactly
    const int src = ei[e];            // edge_index[0] = src (x_j)
    const int dst = ei[E_EDGES + e];  // edge_index[1] = dst (x_i)

    float acc[64];
#pragma unroll
    for (int c = 0; c < 64; ++c) acc[c] = 0.f;

#pragma unroll 1
    for (int half = 0; half < 2; ++half) {
        // h[0:64] = x[dst] -> W0 rows 0..63 ; h[64:128] = x[src] -> rows 64..127
        const int row = half ? src : dst;
        const float4* r = (const float4*)(x + (size_t)row * 64);
        const float* wbase = wlds + half * 4096;
        float4 hv = r[0];
#pragma unroll 1
        for (int k4 = 0; k4 < 16; ++k4) {
            float4 hn = r[(k4 + 1) & 15];  // prefetch (wraps harmlessly at end)
            const float* wk = wbase + k4 * 256;
#pragma unroll
            for (int j = 0; j < 4; ++j) {
                const float hj = (j == 0) ? hv.x : (j == 1) ? hv.y : (j == 2) ? hv.z : hv.w;
                const float4* wrow = (const float4*)(wk + j * 64);
#pragma unroll
                for (int c4 = 0; c4 < 16; ++c4) {
                    float4 w = wrow[c4];
                    acc[c4 * 4 + 0] = fmaf(hj, w.x, acc[c4 * 4 + 0]);
                    acc[c4 * 4 + 1] = fmaf(hj, w.y, acc[c4 * 4 + 1]);
                    acc[c4 * 4 + 2] = fmaf(hj, w.z, acc[c4 * 4 + 2]);
                    acc[c4 * 4 + 3] = fmaf(hj, w.w, acc[c4 * 4 + 3]);
                }
            }
            hv = hn;
        }
    }

    float4* to = (float4*)(t + (size_t)e * 64);
#pragma unroll
    for (int q = 0; q < 16; ++q)
        to[q] = make_float4(acc[4 * q], acc[4 * q + 1], acc[4 * q + 2], acc[4 * q + 3]);

    atomicAdd(&counts[dst], 1.0f);
}

// ---------------------------------------------------------------------------
// Column sums + sums of squares over all E rows of t (for BN stats).
// Coalesced float4 reads; per-block LDS reduction; 256 atomics per column.
// sums[0..63] = sum, sums[64..127] = sumsq.
// ---------------------------------------------------------------------------
__global__ __launch_bounds__(256) void k_stats(
    const float* __restrict__ t, float* __restrict__ sums)
{
    const int cq = threadIdx.x & 15;  // which float4 of the 64-col row
    const int r  = threadIdx.x >> 4;  // row within block tile (0..15)
    float s0 = 0, s1 = 0, s2 = 0, s3 = 0, q0 = 0, q1 = 0, q2 = 0, q3 = 0;
    for (long base = (long)blockIdx.x * 16; base < E_EDGES; base += (long)gridDim.x * 16) {
        const float4 v = *(const float4*)(t + (base + r) * 64 + cq * 4);
        s0 += v.x; q0 = fmaf(v.x, v.x, q0);
        s1 += v.y; q1 = fmaf(v.y, v.y, q1);
        s2 += v.z; q2 = fmaf(v.z, v.z, q2);
        s3 += v.w; q3 = fmaf(v.w, v.w, q3);
    }
    __shared__ float red[256 * 8];
    float* m = red + threadIdx.x * 8;
    m[0] = s0; m[1] = s1; m[2] = s2; m[3] = s3;
    m[4] = q0; m[5] = q1; m[6] = q2; m[7] = q3;
    __syncthreads();
    if (threadIdx.x < 16) {
        float a[8] = {0, 0, 0, 0, 0, 0, 0, 0};
        for (int rr = 0; rr < 16; ++rr) {
            const float* p = red + (rr * 16 + threadIdx.x) * 8;
#pragma unroll
            for (int i2 = 0; i2 < 8; ++i2) a[i2] += p[i2];
        }
#pragma unroll
        for (int i2 = 0; i2 < 4; ++i2) {
            atomicAdd(&sums[threadIdx.x * 4 + i2], a[i2]);
            atomicAdd(&sums[64 + threadIdx.x * 4 + i2], a[i2 + 4]);
        }
    }
}

// ---------------------------------------------------------------------------
// BN -> per-column affine: a = g*rsqrt(var+eps), c = beta - mu*a.
// (Linear bias cancels: it shifts mu identically.)
// ---------------------------------------------------------------------------
__global__ void k_bnfinalize(
    const float* __restrict__ sums, const float* __restrict__ g,
    const float* __restrict__ beta, float* __restrict__ coefs)
{
    const int c = threadIdx.x;  // 64 threads
    const float inv_e = 1.f / (float)E_EDGES;
    const float mu  = sums[c] * inv_e;
    const float var = sums[64 + c] * inv_e - mu * mu;
    const float a = g[c] * rsqrtf(var + BN_EPS);
    coefs[c] = a;
    coefs[64 + c] = beta[c] - mu * a;
}

// ---------------------------------------------------------------------------
// Mid layer: t[e] <- relu(t[e]*a + c) @ W   (in place per edge row).
// ---------------------------------------------------------------------------
__global__ __launch_bounds__(256) void k_gemm_mid(
    float* __restrict__ t, const float* __restrict__ W,
    const float* __restrict__ coefs)
{
    __shared__ float wlds[64 * 64];
    __shared__ float clds[128];
    {
        float4* wv = (float4*)wlds;
        const float4* w4 = (const float4*)W;
        for (int i = threadIdx.x; i < 64 * 16; i += 256) wv[i] = w4[i];
        if (threadIdx.x < 32)
            ((float4*)clds)[threadIdx.x] = ((const float4*)coefs)[threadIdx.x];
    }
    __syncthreads();

    const int e = blockIdx.x * 256 + threadIdx.x;
    float4* trow = (float4*)(t + (size_t)e * 64);

    float acc[64];
#pragma unroll
    for (int c = 0; c < 64; ++c) acc[c] = 0.f;

    float4 hv = trow[0];
#pragma unroll 1
    for (int k4 = 0; k4 < 16; ++k4) {
        float4 hn = trow[(k4 + 1) & 15];
        const float4 av = ((const float4*)clds)[k4];
        const float4 cv = ((const float4*)(clds + 64))[k4];
        const float h0 = fmaxf(fmaf(hv.x, av.x, cv.x), 0.f);
        const float h1 = fmaxf(fmaf(hv.y, av.y, cv.y), 0.f);
        const float h2 = fmaxf(fmaf(hv.z, av.z, cv.z), 0.f);
        const float h3 = fmaxf(fmaf(hv.w, av.w, cv.w), 0.f);
        const float* wk = wlds + k4 * 256;
#pragma unroll
        for (int j = 0; j < 4; ++j) {
            const float hj = (j == 0) ? h0 : (j == 1) ? h1 : (j == 2) ? h2 : h3;
            const float4* wrow = (const float4*)(wk + j * 64);
#pragma unroll
            for (int c4 = 0; c4 < 16; ++c4) {
                float4 w = wrow[c4];
                acc[c4 * 4 + 0] = fmaf(hj, w.x, acc[c4 * 4 + 0]);
                acc[c4 * 4 + 1] = fmaf(hj, w.y, acc[c4 * 4 + 1]);
                acc[c4 * 4 + 2] = fmaf(hj, w.z, acc[c4 * 4 + 2]);
                acc[c4 * 4 + 3] = fmaf(hj, w.w, acc[c4 * 4 + 3]);
            }
        }
        hv = hn;
    }

    float4* to = trow;
#pragma unroll
    for (int q = 0; q < 16; ++q)
        to[q] = make_float4(acc[4 * q], acc[4 * q + 1], acc[4 * q + 2], acc[4 * q + 3]);
}

// ---------------------------------------------------------------------------
// Final layer apply: ea = relu(t2*a2 + c2) written in place (this IS the
// edge_activations output region), plus scatter-add into node accumulator.
// ---------------------------------------------------------------------------
__global__ __launch_bounds__(256) void k_apply_scatter(
    float* __restrict__ tea, const int* __restrict__ ei,
    const float* __restrict__ coefs, float* __restrict__ accum)
{
    __shared__ float clds[128];
    if (threadIdx.x < 32)
        ((float4*)clds)[threadIdx.x] = ((const float4*)coefs)[threadIdx.x];
    __syncthreads();

    const int e = blockIdx.x * 256 + threadIdx.x;
    const int dst = ei[E_EDGES + e];
    float4* row = (float4*)(tea + (size_t)e * 64);
    float* ab = accum + (size_t)dst * 64;
#pragma unroll 1
    for (int q = 0; q < 16; ++q) {
        float4 v = row[q];
        const float4 a = ((const float4*)clds)[q];
        const float4 c = ((const float4*)(clds + 64))[q];
        v.x = fmaxf(fmaf(v.x, a.x, c.x), 0.f);
        v.y = fmaxf(fmaf(v.y, a.y, c.y), 0.f);
        v.z = fmaxf(fmaf(v.z, a.z, c.z), 0.f);
        v.w = fmaxf(fmaf(v.w, a.w, c.w), 0.f);
        row[q] = v;
        atomicAdd(ab + 4 * q + 0, v.x);
        atomicAdd(ab + 4 * q + 1, v.y);
        atomicAdd(ab + 4 * q + 2, v.z);
        atomicAdd(ab + 4 * q + 3, v.w);
    }
}

// ---------------------------------------------------------------------------
// out[n] = accum[n] / max(counts[n], 1)  (in place on d_out's node region)
// ---------------------------------------------------------------------------
__global__ __launch_bounds__(256) void k_norm(
    float* __restrict__ out, const float* __restrict__ counts)
{
    const int i = blockIdx.x * 256 + threadIdx.x;  // over NN*16
    const int n = i >> 4, q = i & 15;
    const float inv = 1.f / fmaxf(counts[n], 1.f);
    float4* p = (float4*)(out + (size_t)n * 64 + q * 4);
    float4 v = *p;
    v.x *= inv; v.y *= inv; v.z *= inv; v.w *= inv;
    *p = v;
}

extern "C" void kernel_launch(void* const* d_in, const int* in_sizes, int n_in,
                              void* d_out, int out_size, void* d_ws, size_t ws_size,
                              hipStream_t stream)
{
    (void)in_sizes; (void)n_in; (void)out_size; (void)ws_size;

    const float* x     = (const float*)d_in[0];
    const int*   ei    = (const int*)d_in[1];
    const float* W0    = (const float*)d_in[2];
    const float* g0    = (const float*)d_in[4];
    const float* beta0 = (const float*)d_in[5];
    const float* W1    = (const float*)d_in[6];
    const float* g1    = (const float*)d_in[8];
    const float* beta1 = (const float*)d_in[9];
    const float* W2    = (const float*)d_in[10];
    const float* g2    = (const float*)d_in[12];
    const float* beta2 = (const float*)d_in[13];

    float* out = (float*)d_out;                    // [NN*64] node output / accum
    float* tea = out + (size_t)NN * 64;            // [E*64] t buffer == edge_activations out

    char*  ws     = (char*)d_ws;
    float* counts = (float*)ws;                    // NN floats @ 0
    float* sums0  = (float*)(ws + 204800);         // 3 x 128 floats
    float* sums1  = sums0 + 128;
    float* sums2  = sums0 + 256;
    float* coef0  = sums0 + 384;                   // 3 x 128 floats (a | c)
    float* coef1  = sums0 + 512;
    float* coef2  = sums0 + 640;

    // zero: node accumulator (in d_out) + counts + stat sums (ws poisoned 0xAA)
    hipMemsetAsync(d_out, 0, (size_t)NN * 64 * sizeof(float), stream);
    hipMemsetAsync(d_ws, 0, 204800 + 384 * sizeof(float), stream);

    const int GB = E_EDGES / 256;  // 3125, exact

    k_gemm0<<<GB, 256, 0, stream>>>(x, ei, W0, tea, counts);
    k_stats<<<1024, 256, 0, stream>>>(tea, sums0);
    k_bnfinalize<<<1, 64, 0, stream>>>(sums0, g0, beta0, coef0);

    k_gemm_mid<<<GB, 256, 0, stream>>>(tea, W1, coef0);
    k_stats<<<1024, 256, 0, stream>>>(tea, sums1);
    k_bnfinalize<<<1, 64, 0, stream>>>(sums1, g1, beta1, coef1);

    k_gemm_mid<<<GB, 256, 0, stream>>>(tea, W2, coef1);
    k_stats<<<1024, 256, 0, stream>>>(tea, sums2);
    k_bnfinalize<<<1, 64, 0, stream>>>(sums2, g2, beta2, coef2);

    k_apply_scatter<<<GB, 256, 0, stream>>>(tea, ei, coef2, out);
    k_norm<<<(NN * 16) / 256, 256, 0, stream>>>(out, counts);
}

// Round 2
// 1404.302 us; speedup vs baseline: 2.7220x; 2.7220x over previous
//
#include <hip/hip_runtime.h>
#include <hip/hip_bf16.h>

#define E_EDGES 800000
#define NN 50000
#define BN_EPS 1e-5f

// ---------------------------------------------------------------------------
// Layer 0: h = concat(x[dst], x[src]) @ W0   (bias b0 cancels under BN)
// thread = 1 edge, 64 fp32 accumulators, W0 (128x64, 32KB) in LDS.
// Also builds the int dst-histogram for the CSR scatter.
// ---------------------------------------------------------------------------
__global__ __launch_bounds__(256) void k_gemm0(
    const float* __restrict__ x, const int* __restrict__ ei,
    const float* __restrict__ W0, float* __restrict__ t,
    int* __restrict__ counts)
{
    __shared__ float wlds[128 * 64];
    {
        float4* wv = (float4*)wlds;
        const float4* w4 = (const float4*)W0;
        for (int i = threadIdx.x; i < 128 * 16; i += 256) wv[i] = w4[i];
    }
    __syncthreads();

    const int e   = blockIdx.x * 256 + threadIdx.x;  // grid = E/256 exactly
    const int src = ei[e];            // edge_index[0] = src (x_j)
    const int dst = ei[E_EDGES + e];  // edge_index[1] = dst (x_i)

    float acc[64];
#pragma unroll
    for (int c = 0; c < 64; ++c) acc[c] = 0.f;

#pragma unroll 1
    for (int half = 0; half < 2; ++half) {
        // h[0:64] = x[dst] -> W0 rows 0..63 ; h[64:128] = x[src] -> rows 64..127
        const int row = half ? src : dst;
        const float4* r = (const float4*)(x + (size_t)row * 64);
        const float* wbase = wlds + half * 4096;
        float4 hv = r[0];
#pragma unroll 1
        for (int k4 = 0; k4 < 16; ++k4) {
            float4 hn = r[(k4 + 1) & 15];  // prefetch (wraps harmlessly at end)
            const float* wk = wbase + k4 * 256;
#pragma unroll
            for (int j = 0; j < 4; ++j) {
                const float hj = (j == 0) ? hv.x : (j == 1) ? hv.y : (j == 2) ? hv.z : hv.w;
                const float4* wrow = (const float4*)(wk + j * 64);
#pragma unroll
                for (int c4 = 0; c4 < 16; ++c4) {
                    float4 w = wrow[c4];
                    acc[c4 * 4 + 0] = fmaf(hj, w.x, acc[c4 * 4 + 0]);
                    acc[c4 * 4 + 1] = fmaf(hj, w.y, acc[c4 * 4 + 1]);
                    acc[c4 * 4 + 2] = fmaf(hj, w.z, acc[c4 * 4 + 2]);
                    acc[c4 * 4 + 3] = fmaf(hj, w.w, acc[c4 * 4 + 3]);
                }
            }
            hv = hn;
        }
    }

    float4* to = (float4*)(t + (size_t)e * 64);
#pragma unroll
    for (int q = 0; q < 16; ++q)
        to[q] = make_float4(acc[4 * q], acc[4 * q + 1], acc[4 * q + 2], acc[4 * q + 3]);

    atomicAdd(&counts[dst], 1);
}

// ---------------------------------------------------------------------------
// Column sums + sums of squares over all E rows of t (for BN stats).
// sums[0..63] = sum, sums[64..127] = sumsq.
// ---------------------------------------------------------------------------
__global__ __launch_bounds__(256) void k_stats(
    const float* __restrict__ t, float* __restrict__ sums)
{
    const int cq = threadIdx.x & 15;  // which float4 of the 64-col row
    const int r  = threadIdx.x >> 4;  // row within block tile (0..15)
    float s0 = 0, s1 = 0, s2 = 0, s3 = 0, q0 = 0, q1 = 0, q2 = 0, q3 = 0;
    for (long base = (long)blockIdx.x * 16; base < E_EDGES; base += (long)gridDim.x * 16) {
        const float4 v = *(const float4*)(t + (base + r) * 64 + cq * 4);
        s0 += v.x; q0 = fmaf(v.x, v.x, q0);
        s1 += v.y; q1 = fmaf(v.y, v.y, q1);
        s2 += v.z; q2 = fmaf(v.z, v.z, q2);
        s3 += v.w; q3 = fmaf(v.w, v.w, q3);
    }
    __shared__ float red[256 * 8];
    float* m = red + threadIdx.x * 8;
    m[0] = s0; m[1] = s1; m[2] = s2; m[3] = s3;
    m[4] = q0; m[5] = q1; m[6] = q2; m[7] = q3;
    __syncthreads();
    if (threadIdx.x < 16) {
        float a[8] = {0, 0, 0, 0, 0, 0, 0, 0};
        for (int rr = 0; rr < 16; ++rr) {
            const float* p = red + (rr * 16 + threadIdx.x) * 8;
#pragma unroll
            for (int i2 = 0; i2 < 8; ++i2) a[i2] += p[i2];
        }
#pragma unroll
        for (int i2 = 0; i2 < 4; ++i2) {
            atomicAdd(&sums[threadIdx.x * 4 + i2], a[i2]);
            atomicAdd(&sums[64 + threadIdx.x * 4 + i2], a[i2 + 4]);
        }
    }
}

// ---------------------------------------------------------------------------
// BN -> per-column affine: a = g*rsqrt(var+eps), c = beta - mu*a.
// ---------------------------------------------------------------------------
__global__ void k_bnfinalize(
    const float* __restrict__ sums, const float* __restrict__ g,
    const float* __restrict__ beta, float* __restrict__ coefs)
{
    const int c = threadIdx.x;  // 64 threads
    const float inv_e = 1.f / (float)E_EDGES;
    const float mu  = sums[c] * inv_e;
    const float var = sums[64 + c] * inv_e - mu * mu;
    const float a = g[c] * rsqrtf(var + BN_EPS);
    coefs[c] = a;
    coefs[64 + c] = beta[c] - mu * a;
}

// ---------------------------------------------------------------------------
// Exclusive scan of counts[NN] -> offsets, cursor. Single block, 256 threads.
// ---------------------------------------------------------------------------
__global__ __launch_bounds__(256) void k_scan(
    const int* __restrict__ counts, int* __restrict__ offsets,
    int* __restrict__ cursor)
{
    const int CHUNK = (NN + 255) / 256;  // 196
    const int t = threadIdx.x;
    const int beg = t * CHUNK;
    const int end = (beg + CHUNK < NN) ? beg + CHUNK : NN;
    int mysum = 0;
    for (int i = beg; i < end; ++i) mysum += counts[i];

    __shared__ int sd[256];
    sd[t] = mysum;
    __syncthreads();
    int run = mysum;
    for (int off = 1; off < 256; off <<= 1) {
        int v = (t >= off) ? sd[t - off] : 0;
        __syncthreads();
        sd[t] += v;
        __syncthreads();
    }
    int prefix = sd[t] - run;  // exclusive prefix of this thread's chunk

    for (int i = beg; i < end; ++i) {
        offsets[i] = prefix;
        cursor[i] = prefix;
        prefix += counts[i];
    }
}

// ---------------------------------------------------------------------------
// CSR fill: eidx[cursor[dst]++] = e  (int atomics only)
// ---------------------------------------------------------------------------
__global__ __launch_bounds__(256) void k_fill(
    const int* __restrict__ ei, int* __restrict__ cursor,
    int* __restrict__ eidx)
{
    const int e = blockIdx.x * 256 + threadIdx.x;
    const int dst = ei[E_EDGES + e];
    const int pos = atomicAdd(&cursor[dst], 1);
    eidx[pos] = e;
}

// ---------------------------------------------------------------------------
// Mid layer: t[e] <- relu(t[e]*a + c) @ W   (in place per edge row).
// ---------------------------------------------------------------------------
__global__ __launch_bounds__(256) void k_gemm_mid(
    float* __restrict__ t, const float* __restrict__ W,
    const float* __restrict__ coefs)
{
    __shared__ float wlds[64 * 64];
    __shared__ float clds[128];
    {
        float4* wv = (float4*)wlds;
        const float4* w4 = (const float4*)W;
        for (int i = threadIdx.x; i < 64 * 16; i += 256) wv[i] = w4[i];
        if (threadIdx.x < 32)
            ((float4*)clds)[threadIdx.x] = ((const float4*)coefs)[threadIdx.x];
    }
    __syncthreads();

    const int e = blockIdx.x * 256 + threadIdx.x;
    float4* trow = (float4*)(t + (size_t)e * 64);

    float acc[64];
#pragma unroll
    for (int c = 0; c < 64; ++c) acc[c] = 0.f;

    float4 hv = trow[0];
#pragma unroll 1
    for (int k4 = 0; k4 < 16; ++k4) {
        float4 hn = trow[(k4 + 1) & 15];
        const float4 av = ((const float4*)clds)[k4];
        const float4 cv = ((const float4*)(clds + 64))[k4];
        const float h0 = fmaxf(fmaf(hv.x, av.x, cv.x), 0.f);
        const float h1 = fmaxf(fmaf(hv.y, av.y, cv.y), 0.f);
        const float h2 = fmaxf(fmaf(hv.z, av.z, cv.z), 0.f);
        const float h3 = fmaxf(fmaf(hv.w, av.w, cv.w), 0.f);
        const float* wk = wlds + k4 * 256;
#pragma unroll
        for (int j = 0; j < 4; ++j) {
            const float hj = (j == 0) ? h0 : (j == 1) ? h1 : (j == 2) ? h2 : h3;
            const float4* wrow = (const float4*)(wk + j * 64);
#pragma unroll
            for (int c4 = 0; c4 < 16; ++c4) {
                float4 w = wrow[c4];
                acc[c4 * 4 + 0] = fmaf(hj, w.x, acc[c4 * 4 + 0]);
                acc[c4 * 4 + 1] = fmaf(hj, w.y, acc[c4 * 4 + 1]);
                acc[c4 * 4 + 2] = fmaf(hj, w.z, acc[c4 * 4 + 2]);
                acc[c4 * 4 + 3] = fmaf(hj, w.w, acc[c4 * 4 + 3]);
            }
        }
        hv = hn;
    }

    float4* to = trow;
#pragma unroll
    for (int q = 0; q < 16; ++q)
        to[q] = make_float4(acc[4 * q], acc[4 * q + 1], acc[4 * q + 2], acc[4 * q + 3]);
}

// ---------------------------------------------------------------------------
// Final: per node (one 64-lane wave, lane=column), walk the CSR edge list:
// read t2 row, apply BN2 affine+relu, write edge_activations in place,
// accumulate; out[node] = acc / max(cnt,1). No fp32 atomics anywhere.
// ---------------------------------------------------------------------------
__global__ __launch_bounds__(256) void k_gather_apply(
    float* __restrict__ tea, const int* __restrict__ offsets,
    const int* __restrict__ counts, const int* __restrict__ eidx,
    const float* __restrict__ coefs, float* __restrict__ out)
{
    const int node = blockIdx.x * 4 + (threadIdx.x >> 6);  // 4 waves/block
    const int lane = threadIdx.x & 63;
    const float a = coefs[lane];
    const float c = coefs[64 + lane];

    const int beg = offsets[node];
    const int cnt = counts[node];
    const int end = beg + cnt;

    float acc = 0.f;
    int i = beg;
    for (; i + 1 < end; i += 2) {
        const int e0 = eidx[i], e1 = eidx[i + 1];
        float v0 = tea[(size_t)e0 * 64 + lane];
        float v1 = tea[(size_t)e1 * 64 + lane];
        v0 = fmaxf(fmaf(v0, a, c), 0.f);
        v1 = fmaxf(fmaf(v1, a, c), 0.f);
        tea[(size_t)e0 * 64 + lane] = v0;
        tea[(size_t)e1 * 64 + lane] = v1;
        acc += v0 + v1;
    }
    if (i < end) {
        const int e0 = eidx[i];
        float v0 = tea[(size_t)e0 * 64 + lane];
        v0 = fmaxf(fmaf(v0, a, c), 0.f);
        tea[(size_t)e0 * 64 + lane] = v0;
        acc += v0;
    }
    out[(size_t)node * 64 + lane] = acc / fmaxf((float)cnt, 1.f);
}

extern "C" void kernel_launch(void* const* d_in, const int* in_sizes, int n_in,
                              void* d_out, int out_size, void* d_ws, size_t ws_size,
                              hipStream_t stream)
{
    (void)in_sizes; (void)n_in; (void)out_size; (void)ws_size;

    const float* x     = (const float*)d_in[0];
    const int*   ei    = (const int*)d_in[1];
    const float* W0    = (const float*)d_in[2];
    const float* g0    = (const float*)d_in[4];
    const float* beta0 = (const float*)d_in[5];
    const float* W1    = (const float*)d_in[6];
    const float* g1    = (const float*)d_in[8];
    const float* beta1 = (const float*)d_in[9];
    const float* W2    = (const float*)d_in[10];
    const float* g2    = (const float*)d_in[12];
    const float* beta2 = (const float*)d_in[13];

    float* out = (float*)d_out;                    // [NN*64] node output
    float* tea = out + (size_t)NN * 64;            // [E*64] t buffer == edge_activations out

    char* ws      = (char*)d_ws;
    int*  counts  = (int*)ws;                       // NN ints @ 0
    int*  offsets = (int*)(ws + 200000);            // NN ints
    int*  cursor  = (int*)(ws + 400000);            // NN ints
    float* sums0  = (float*)(ws + 600000);          // 3 x 128 floats
    float* sums1  = sums0 + 128;
    float* sums2  = sums0 + 256;
    float* coef0  = sums0 + 384;                    // 3 x 128 floats (a | c)
    float* coef1  = sums0 + 512;
    float* coef2  = sums0 + 640;
    int*  eidx    = (int*)(ws + 640000);            // E ints (3.2 MB)

    // zero: counts histogram + stat sums (ws is poisoned 0xAA by harness)
    hipMemsetAsync(counts, 0, NN * sizeof(int), stream);
    hipMemsetAsync(sums0, 0, 384 * sizeof(float), stream);

    const int GB = E_EDGES / 256;  // 3125, exact

    k_gemm0<<<GB, 256, 0, stream>>>(x, ei, W0, tea, counts);
    k_stats<<<1024, 256, 0, stream>>>(tea, sums0);
    k_bnfinalize<<<1, 64, 0, stream>>>(sums0, g0, beta0, coef0);

    // CSR build (counts final after gemm0)
    k_scan<<<1, 256, 0, stream>>>(counts, offsets, cursor);
    k_fill<<<GB, 256, 0, stream>>>(ei, cursor, eidx);

    k_gemm_mid<<<GB, 256, 0, stream>>>(tea, W1, coef0);
    k_stats<<<1024, 256, 0, stream>>>(tea, sums1);
    k_bnfinalize<<<1, 64, 0, stream>>>(sums1, g1, beta1, coef1);

    k_gemm_mid<<<GB, 256, 0, stream>>>(tea, W2, coef1);
    k_stats<<<1024, 256, 0, stream>>>(tea, sums2);
    k_bnfinalize<<<1, 64, 0, stream>>>(sums2, g2, beta2, coef2);

    k_gather_apply<<<NN / 4, 256, 0, stream>>>(tea, offsets, counts, eidx, coef2, out);
}

// Round 3
// 1183.925 us; speedup vs baseline: 3.2286x; 1.1861x over previous
//
#include <hip/hip_runtime.h>
#include <hip/hip_bf16.h>

#define E_EDGES 800000
#define NN 50000
#define BN_EPS 1e-5f

typedef __bf16 bf16x8 __attribute__((ext_vector_type(8)));
typedef float f32x4 __attribute__((ext_vector_type(4)));

// ---------------------------------------------------------------------------
// Prep: transpose + bf16-convert the weight matrices.
// ---------------------------------------------------------------------------
__global__ void k_prep(const float* __restrict__ W0, const float* __restrict__ W1,
                       const float* __restrict__ W2, __bf16* __restrict__ W0t_top,
                       __bf16* __restrict__ W0t_bot, __bf16* __restrict__ Wt1,
                       __bf16* __restrict__ Wt2)
{
    for (int i = threadIdx.x; i < 4096; i += 256) {
        const int n = i >> 6, k = i & 63;
        W0t_top[n * 64 + k] = (__bf16)W0[k * 64 + n];
        W0t_bot[n * 64 + k] = (__bf16)W0[(64 + k) * 64 + n];
        Wt1[n * 64 + k] = (__bf16)W1[k * 64 + n];
        Wt2[n * 64 + k] = (__bf16)W2[k * 64 + n];
    }
}

// ---------------------------------------------------------------------------
// Node GEMM: P = x @ W0_top, Q = x @ W0_bot  (both 50000x64, bf16 out).
// MFMA 16x16x32 bf16. Wave = one 16-row strip. No LDS, no barriers.
// ---------------------------------------------------------------------------
__global__ __launch_bounds__(256) void k_gemm_node(
    const float* __restrict__ x, const __bf16* __restrict__ W0t_top,
    const __bf16* __restrict__ W0t_bot, __bf16* __restrict__ P,
    __bf16* __restrict__ Q)
{
    const int wave = threadIdx.x >> 6;
    const int strip = blockIdx.x * 4 + wave;
    if (strip >= NN / 16) return;  // 3125 strips
    const int lane = threadIdx.x & 63;
    const int quad = lane >> 4, lr = lane & 15;

    bf16x8 bT[2][4], bB[2][4];
#pragma unroll
    for (int s = 0; s < 2; ++s)
#pragma unroll
        for (int nt = 0; nt < 4; ++nt) {
            const int off = (nt * 16 + lr) * 64 + s * 32 + quad * 8;
            bT[s][nt] = *(const bf16x8*)(W0t_top + off);
            bB[s][nt] = *(const bf16x8*)(W0t_bot + off);
        }

    f32x4 accP[4], accQ[4];
#pragma unroll
    for (int nt = 0; nt < 4; ++nt) {
        accP[nt] = (f32x4){0.f, 0.f, 0.f, 0.f};
        accQ[nt] = (f32x4){0.f, 0.f, 0.f, 0.f};
    }

    const int m = strip * 16 + lr;
#pragma unroll
    for (int s = 0; s < 2; ++s) {
        const float4* ap = (const float4*)(x + (size_t)m * 64 + s * 32 + quad * 8);
        const float4 v0 = ap[0], v1 = ap[1];
        bf16x8 af;
        af[0] = (__bf16)v0.x; af[1] = (__bf16)v0.y; af[2] = (__bf16)v0.z; af[3] = (__bf16)v0.w;
        af[4] = (__bf16)v1.x; af[5] = (__bf16)v1.y; af[6] = (__bf16)v1.z; af[7] = (__bf16)v1.w;
#pragma unroll
        for (int nt = 0; nt < 4; ++nt) {
            accP[nt] = __builtin_amdgcn_mfma_f32_16x16x32_bf16(af, bT[s][nt], accP[nt], 0, 0, 0);
            accQ[nt] = __builtin_amdgcn_mfma_f32_16x16x32_bf16(af, bB[s][nt], accQ[nt], 0, 0, 0);
        }
    }

#pragma unroll
    for (int nt = 0; nt < 4; ++nt)
#pragma unroll
        for (int r = 0; r < 4; ++r) {
            const int row = strip * 16 + quad * 4 + r;
            const int col = nt * 16 + lr;
            P[(size_t)row * 64 + col] = (__bf16)accP[nt][r];
            Q[(size_t)row * 64 + col] = (__bf16)accQ[nt][r];
        }
}

// ---------------------------------------------------------------------------
// Edge stage 0: t0[e] = P[dst[e]] + Q[src[e]] (fp32 out), fused stats0 +
// counts histogram. 2 threads per edge (32 cols each), grid-stride.
// ---------------------------------------------------------------------------
__global__ __launch_bounds__(256) void k_edge0(
    const __bf16* __restrict__ P, const __bf16* __restrict__ Q,
    const int* __restrict__ ei, float* __restrict__ t0,
    int* __restrict__ counts, float* __restrict__ sums)
{
    float sa[32], sq[32];
#pragma unroll
    for (int j = 0; j < 32; ++j) { sa[j] = 0.f; sq[j] = 0.f; }

    const int stride = gridDim.x * 256;
    for (int s = blockIdx.x * 256 + threadIdx.x; s < 2 * E_EDGES; s += stride) {
        const int e = s >> 1, half = s & 1;
        const int src = ei[e];
        const int dst = ei[E_EDGES + e];
        const bf16x8* pp = (const bf16x8*)(P + (size_t)dst * 64 + half * 32);
        const bf16x8* qp = (const bf16x8*)(Q + (size_t)src * 64 + half * 32);
        bf16x8 pf0 = pp[0], pf1 = pp[1], pf2 = pp[2], pf3 = pp[3];
        bf16x8 qf0 = qp[0], qf1 = qp[1], qf2 = qp[2], qf3 = qp[3];
        float v[32];
#pragma unroll
        for (int j = 0; j < 8; ++j) {
            v[j]      = (float)pf0[j] + (float)qf0[j];
            v[8 + j]  = (float)pf1[j] + (float)qf1[j];
            v[16 + j] = (float)pf2[j] + (float)qf2[j];
            v[24 + j] = (float)pf3[j] + (float)qf3[j];
        }
#pragma unroll
        for (int j = 0; j < 32; ++j) { sa[j] += v[j]; sq[j] = fmaf(v[j], v[j], sq[j]); }
        float4* to = (float4*)(t0 + (size_t)e * 64 + half * 32);
#pragma unroll
        for (int q4 = 0; q4 < 8; ++q4)
            to[q4] = make_float4(v[4 * q4], v[4 * q4 + 1], v[4 * q4 + 2], v[4 * q4 + 3]);
        if (half == 0) atomicAdd(&counts[dst], 1);
    }

#pragma unroll
    for (int off = 2; off < 64; off <<= 1)
#pragma unroll
        for (int j = 0; j < 32; ++j) {
            sa[j] += __shfl_xor(sa[j], off);
            sq[j] += __shfl_xor(sq[j], off);
        }

    __shared__ float red[4][128];
    const int wave = threadIdx.x >> 6, lane = threadIdx.x & 63;
    if (lane < 2) {
        const int cbase = lane * 32;
#pragma unroll
        for (int j = 0; j < 32; ++j) {
            red[wave][cbase + j] = sa[j];
            red[wave][64 + cbase + j] = sq[j];
        }
    }
    __syncthreads();
    if (threadIdx.x < 128) {
        float v2 = red[0][threadIdx.x] + red[1][threadIdx.x] + red[2][threadIdx.x] + red[3][threadIdx.x];
        atomicAdd(&sums[threadIdx.x], v2);
    }
}

// ---------------------------------------------------------------------------
// Exclusive scan of counts[NN] -> offsets, cursor.
// ---------------------------------------------------------------------------
__global__ __launch_bounds__(256) void k_scan(
    const int* __restrict__ counts, int* __restrict__ offsets,
    int* __restrict__ cursor)
{
    const int CHUNK = (NN + 255) / 256;  // 196
    const int t = threadIdx.x;
    const int beg = t * CHUNK;
    const int end = (beg + CHUNK < NN) ? beg + CHUNK : NN;
    int mysum = 0;
    for (int i = beg; i < end; ++i) mysum += counts[i];

    __shared__ int sd[256];
    sd[t] = mysum;
    __syncthreads();
    int run = mysum;
    for (int off = 1; off < 256; off <<= 1) {
        int v = (t >= off) ? sd[t - off] : 0;
        __syncthreads();
        sd[t] += v;
        __syncthreads();
    }
    int prefix = sd[t] - run;
    for (int i = beg; i < end; ++i) {
        offsets[i] = prefix;
        cursor[i] = prefix;
        prefix += counts[i];
    }
}

// ---------------------------------------------------------------------------
// CSR fill: eidx[cursor[dst]++] = e
// ---------------------------------------------------------------------------
__global__ __launch_bounds__(256) void k_fill(
    const int* __restrict__ ei, int* __restrict__ cursor,
    int* __restrict__ eidx)
{
    const int e = blockIdx.x * 256 + threadIdx.x;
    const int dst = ei[E_EDGES + e];
    const int pos = atomicAdd(&cursor[dst], 1);
    eidx[pos] = e;
}

// ---------------------------------------------------------------------------
// Mid layer (MFMA): t[e] <- relu(t[e]*a + c) @ W, in place (fp32 t), fused
// BN-coef prologue (prev-layer sums) and fused next-layer stats epilogue.
// ---------------------------------------------------------------------------
__global__ __launch_bounds__(256) void k_gemm_mid(
    float* __restrict__ t, const __bf16* __restrict__ Wt,
    const float* __restrict__ sums_in, const float* __restrict__ g,
    const float* __restrict__ beta, float* __restrict__ sums_out)
{
    __shared__ float clds[128];
    __shared__ float sred[4][64], qred[4][64];
    if (threadIdx.x < 64) {
        const float inv_e = 1.f / (float)E_EDGES;
        const float mu = sums_in[threadIdx.x] * inv_e;
        const float var = sums_in[64 + threadIdx.x] * inv_e - mu * mu;
        const float a = g[threadIdx.x] * rsqrtf(var + BN_EPS);
        clds[threadIdx.x] = a;
        clds[64 + threadIdx.x] = beta[threadIdx.x] - mu * a;
    }
    __syncthreads();

    const int wave = threadIdx.x >> 6;
    const int strip = blockIdx.x * 4 + wave;  // grid = E/64 exactly
    const int lane = threadIdx.x & 63;
    const int quad = lane >> 4, lr = lane & 15;

    float ar[2][8], cr[2][8];
#pragma unroll
    for (int s = 0; s < 2; ++s)
#pragma unroll
        for (int j = 0; j < 8; ++j) {
            const int k = s * 32 + quad * 8 + j;
            ar[s][j] = clds[k];
            cr[s][j] = clds[64 + k];
        }

    bf16x8 bf[2][4];
#pragma unroll
    for (int s = 0; s < 2; ++s)
#pragma unroll
        for (int nt = 0; nt < 4; ++nt)
            bf[s][nt] = *(const bf16x8*)(Wt + (nt * 16 + lr) * 64 + s * 32 + quad * 8);

    f32x4 acc[4];
#pragma unroll
    for (int nt = 0; nt < 4; ++nt) acc[nt] = (f32x4){0.f, 0.f, 0.f, 0.f};

    const int m = strip * 16 + lr;
#pragma unroll
    for (int s = 0; s < 2; ++s) {
        const float4* ap = (const float4*)(t + (size_t)m * 64 + s * 32 + quad * 8);
        const float4 v0 = ap[0], v1 = ap[1];
        bf16x8 af;
        af[0] = (__bf16)fmaxf(fmaf(v0.x, ar[s][0], cr[s][0]), 0.f);
        af[1] = (__bf16)fmaxf(fmaf(v0.y, ar[s][1], cr[s][1]), 0.f);
        af[2] = (__bf16)fmaxf(fmaf(v0.z, ar[s][2], cr[s][2]), 0.f);
        af[3] = (__bf16)fmaxf(fmaf(v0.w, ar[s][3], cr[s][3]), 0.f);
        af[4] = (__bf16)fmaxf(fmaf(v1.x, ar[s][4], cr[s][4]), 0.f);
        af[5] = (__bf16)fmaxf(fmaf(v1.y, ar[s][5], cr[s][5]), 0.f);
        af[6] = (__bf16)fmaxf(fmaf(v1.z, ar[s][6], cr[s][6]), 0.f);
        af[7] = (__bf16)fmaxf(fmaf(v1.w, ar[s][7], cr[s][7]), 0.f);
#pragma unroll
        for (int nt = 0; nt < 4; ++nt)
            acc[nt] = __builtin_amdgcn_mfma_f32_16x16x32_bf16(af, bf[s][nt], acc[nt], 0, 0, 0);
    }

    float ssum[4], sqq[4];
#pragma unroll
    for (int nt = 0; nt < 4; ++nt) {
        ssum[nt] = 0.f; sqq[nt] = 0.f;
#pragma unroll
        for (int r = 0; r < 4; ++r) {
            const float v = acc[nt][r];
            t[(size_t)(strip * 16 + quad * 4 + r) * 64 + nt * 16 + lr] = v;
            ssum[nt] += v;
            sqq[nt] = fmaf(v, v, sqq[nt]);
        }
    }
#pragma unroll
    for (int nt = 0; nt < 4; ++nt) {
        ssum[nt] += __shfl_xor(ssum[nt], 16); ssum[nt] += __shfl_xor(ssum[nt], 32);
        sqq[nt]  += __shfl_xor(sqq[nt], 16);  sqq[nt]  += __shfl_xor(sqq[nt], 32);
    }
    if (lane < 16) {
#pragma unroll
        for (int nt = 0; nt < 4; ++nt) {
            sred[wave][nt * 16 + lane] = ssum[nt];
            qred[wave][nt * 16 + lane] = sqq[nt];
        }
    }
    __syncthreads();
    if (threadIdx.x < 64) {
        const int c = threadIdx.x;
        atomicAdd(&sums_out[c], sred[0][c] + sred[1][c] + sred[2][c] + sred[3][c]);
        atomicAdd(&sums_out[64 + c], qred[0][c] + qred[1][c] + qred[2][c] + qred[3][c]);
    }
}

// ---------------------------------------------------------------------------
// Final: coef prologue; per node (one wave, lane=column) walk CSR.
// ---------------------------------------------------------------------------
__global__ __launch_bounds__(256) void k_gather_apply(
    float* __restrict__ tea, const int* __restrict__ offsets,
    const int* __restrict__ counts, const int* __restrict__ eidx,
    const float* __restrict__ sums_in, const float* __restrict__ g,
    const float* __restrict__ beta, float* __restrict__ out)
{
    __shared__ float clds[128];
    if (threadIdx.x < 64) {
        const float inv_e = 1.f / (float)E_EDGES;
        const float mu = sums_in[threadIdx.x] * inv_e;
        const float var = sums_in[64 + threadIdx.x] * inv_e - mu * mu;
        const float a = g[threadIdx.x] * rsqrtf(var + BN_EPS);
        clds[threadIdx.x] = a;
        clds[64 + threadIdx.x] = beta[threadIdx.x] - mu * a;
    }
    __syncthreads();

    const int node = blockIdx.x * 4 + (threadIdx.x >> 6);
    const int lane = threadIdx.x & 63;
    const float a = clds[lane];
    const float c = clds[64 + lane];

    const int beg = offsets[node];
    const int cnt = counts[node];
    const int end = beg + cnt;

    float acc = 0.f;
    int i = beg;
    for (; i + 3 < end; i += 4) {
        const int e0 = eidx[i], e1 = eidx[i + 1], e2 = eidx[i + 2], e3 = eidx[i + 3];
        float v0 = tea[(size_t)e0 * 64 + lane];
        float v1 = tea[(size_t)e1 * 64 + lane];
        float v2 = tea[(size_t)e2 * 64 + lane];
        float v3 = tea[(size_t)e3 * 64 + lane];
        v0 = fmaxf(fmaf(v0, a, c), 0.f);
        v1 = fmaxf(fmaf(v1, a, c), 0.f);
        v2 = fmaxf(fmaf(v2, a, c), 0.f);
        v3 = fmaxf(fmaf(v3, a, c), 0.f);
        tea[(size_t)e0 * 64 + lane] = v0;
        tea[(size_t)e1 * 64 + lane] = v1;
        tea[(size_t)e2 * 64 + lane] = v2;
        tea[(size_t)e3 * 64 + lane] = v3;
        acc += (v0 + v1) + (v2 + v3);
    }
    for (; i < end; ++i) {
        const int e0 = eidx[i];
        float v0 = tea[(size_t)e0 * 64 + lane];
        v0 = fmaxf(fmaf(v0, a, c), 0.f);
        tea[(size_t)e0 * 64 + lane] = v0;
        acc += v0;
    }
    out[(size_t)node * 64 + lane] = acc / fmaxf((float)cnt, 1.f);
}

extern "C" void kernel_launch(void* const* d_in, const int* in_sizes, int n_in,
                              void* d_out, int out_size, void* d_ws, size_t ws_size,
                              hipStream_t stream)
{
    (void)in_sizes; (void)n_in; (void)out_size; (void)ws_size;

    const float* x     = (const float*)d_in[0];
    const int*   ei    = (const int*)d_in[1];
    const float* W0    = (const float*)d_in[2];
    const float* g0    = (const float*)d_in[4];
    const float* beta0 = (const float*)d_in[5];
    const float* W1    = (const float*)d_in[6];
    const float* g1    = (const float*)d_in[8];
    const float* beta1 = (const float*)d_in[9];
    const float* W2    = (const float*)d_in[10];
    const float* g2    = (const float*)d_in[12];
    const float* beta2 = (const float*)d_in[13];

    float* out = (float*)d_out;            // [NN*64] node output
    float* tea = out + (size_t)NN * 64;    // [E*64] fp32 t buffer == edge_activations

    char* ws = (char*)d_ws;
    int*    counts  = (int*)(ws + 0);             // 200000 B
    int*    offsets = (int*)(ws + 200704);
    int*    cursor  = (int*)(ws + 401408);
    float*  sums0   = (float*)(ws + 602112);      // 128 f each
    float*  sums1   = (float*)(ws + 602624);
    float*  sums2   = (float*)(ws + 603136);
    __bf16* W0t_top = (__bf16*)(ws + 603648);     // 8192 B each
    __bf16* W0t_bot = (__bf16*)(ws + 611840);
    __bf16* Wt1     = (__bf16*)(ws + 620032);
    __bf16* Wt2     = (__bf16*)(ws + 628224);
    __bf16* P       = (__bf16*)(ws + 636928);     // 6.4 MB
    __bf16* Q       = (__bf16*)(ws + 7036928);    // 6.4 MB
    int*    eidx    = (int*)(ws + 13436928);      // 3.2 MB

    hipMemsetAsync(counts, 0, NN * sizeof(int), stream);
    hipMemsetAsync(sums0, 0, 3 * 512, stream);  // sums0..2 contiguous

    k_prep<<<1, 256, 0, stream>>>(W0, W1, W2, W0t_top, W0t_bot, Wt1, Wt2);
    k_gemm_node<<<782, 256, 0, stream>>>(x, W0t_top, W0t_bot, P, Q);
    k_edge0<<<1563, 256, 0, stream>>>(P, Q, ei, tea, counts, sums0);

    k_scan<<<1, 256, 0, stream>>>(counts, offsets, cursor);
    k_fill<<<E_EDGES / 256, 256, 0, stream>>>(ei, cursor, eidx);

    // BN0 applied inside first mid-GEMM (produces h1), BN1 inside second
    // (produces h2), BN2 applied in the gather/apply epilogue.
    k_gemm_mid<<<E_EDGES / 64, 256, 0, stream>>>(tea, Wt1, sums0, g0, beta0, sums1);
    k_gemm_mid<<<E_EDGES / 64, 256, 0, stream>>>(tea, Wt2, sums1, g1, beta1, sums2);

    k_gather_apply<<<NN / 4, 256, 0, stream>>>(tea, offsets, counts, eidx,
                                               sums2, g2, beta2, out);
}

// Round 4
// 707.584 us; speedup vs baseline: 5.4021x; 1.6732x over previous
//
#include <hip/hip_runtime.h>
#include <hip/hip_bf16.h>

#define E_EDGES 800000
#define NN 50000
#define BN_EPS 1e-5f

typedef __bf16 bf16x8 __attribute__((ext_vector_type(8)));
typedef __bf16 bf16x4 __attribute__((ext_vector_type(4)));
typedef float f32x4 __attribute__((ext_vector_type(4)));

// ---------------------------------------------------------------------------
// Prep: transpose + bf16-convert weights. Wt[n][k] = W[k][n].
// ---------------------------------------------------------------------------
__global__ void k_prep(const float* __restrict__ W0, const float* __restrict__ W1,
                       const float* __restrict__ W2, __bf16* __restrict__ W0t_top,
                       __bf16* __restrict__ W0t_bot, __bf16* __restrict__ Wt1,
                       __bf16* __restrict__ Wt2)
{
    for (int i = threadIdx.x; i < 4096; i += 256) {
        const int n = i >> 6, k = i & 63;
        W0t_top[n * 64 + k] = (__bf16)W0[k * 64 + n];
        W0t_bot[n * 64 + k] = (__bf16)W0[(64 + k) * 64 + n];
        Wt1[n * 64 + k] = (__bf16)W1[k * 64 + n];
        Wt2[n * 64 + k] = (__bf16)W2[k * 64 + n];
    }
}

// ---------------------------------------------------------------------------
// dst-degree histogram (int atomics, ~16 per address).
// ---------------------------------------------------------------------------
__global__ __launch_bounds__(256) void k_count(
    const int* __restrict__ ei, int* __restrict__ counts)
{
    const int e = blockIdx.x * 256 + threadIdx.x;
    atomicAdd(&counts[ei[E_EDGES + e]], 1);
}

// ---------------------------------------------------------------------------
// Exclusive scan of counts[NN] -> offsets, cursor.
// ---------------------------------------------------------------------------
__global__ __launch_bounds__(256) void k_scan(
    const int* __restrict__ counts, int* __restrict__ offsets,
    int* __restrict__ cursor)
{
    const int CHUNK = (NN + 255) / 256;  // 196
    const int t = threadIdx.x;
    const int beg = t * CHUNK;
    const int end = (beg + CHUNK < NN) ? beg + CHUNK : NN;
    int mysum = 0;
    for (int i = beg; i < end; ++i) mysum += counts[i];

    __shared__ int sd[256];
    sd[t] = mysum;
    __syncthreads();
    int run = mysum;
    for (int off = 1; off < 256; off <<= 1) {
        int v = (t >= off) ? sd[t - off] : 0;
        __syncthreads();
        sd[t] += v;
        __syncthreads();
    }
    int prefix = sd[t] - run;
    for (int i = beg; i < end; ++i) {
        offsets[i] = prefix;
        cursor[i] = prefix;
        prefix += counts[i];
    }
}

// ---------------------------------------------------------------------------
// CSR fill: eidx[cursor[dst]++] = e
// ---------------------------------------------------------------------------
__global__ __launch_bounds__(256) void k_fill(
    const int* __restrict__ ei, int* __restrict__ cursor,
    int* __restrict__ eidx)
{
    const int e = blockIdx.x * 256 + threadIdx.x;
    const int dst = ei[E_EDGES + e];
    const int pos = atomicAdd(&cursor[dst], 1);
    eidx[pos] = e;
}

// ---------------------------------------------------------------------------
// Node GEMM (swapped operands): P = x @ W0_top, Q = x @ W0_bot (bf16 out).
// A = Wt rows (m=out-feature), B = 16-node group (n=node), k=in-feature.
// D[m][n]: lane(quad,lr) holds node=lr, features mt*16+quad*4+r -> packed
// 8B bf16x4 stores, fully contiguous per lane.
// ---------------------------------------------------------------------------
__global__ __launch_bounds__(256) void k_gemm_node(
    const float* __restrict__ x, const __bf16* __restrict__ W0t_top,
    const __bf16* __restrict__ W0t_bot, __bf16* __restrict__ P,
    __bf16* __restrict__ Q)
{
    const int wave = threadIdx.x >> 6;
    const int grp = blockIdx.x * 4 + wave;
    if (grp >= NN / 16) return;  // 3125 groups
    const int lane = threadIdx.x & 63;
    const int quad = lane >> 4, lr = lane & 15;

    // A fragments: [which][mt][s]
    bf16x8 aT[4][2], aB[4][2];
#pragma unroll
    for (int mt = 0; mt < 4; ++mt)
#pragma unroll
        for (int s = 0; s < 2; ++s) {
            const int off = (mt * 16 + lr) * 64 + s * 32 + quad * 8;
            aT[mt][s] = *(const bf16x8*)(W0t_top + off);
            aB[mt][s] = *(const bf16x8*)(W0t_bot + off);
        }

    // B fragment: x row of node grp*16+lr, k = s*32+quad*8+j
    const int node = grp * 16 + lr;
    bf16x8 bx[2];
#pragma unroll
    for (int s = 0; s < 2; ++s) {
        const float4* ap = (const float4*)(x + (size_t)node * 64 + s * 32 + quad * 8);
        const float4 v0 = ap[0], v1 = ap[1];
        bx[s][0] = (__bf16)v0.x; bx[s][1] = (__bf16)v0.y;
        bx[s][2] = (__bf16)v0.z; bx[s][3] = (__bf16)v0.w;
        bx[s][4] = (__bf16)v1.x; bx[s][5] = (__bf16)v1.y;
        bx[s][6] = (__bf16)v1.z; bx[s][7] = (__bf16)v1.w;
    }

    f32x4 accP[4], accQ[4];
#pragma unroll
    for (int mt = 0; mt < 4; ++mt) {
        accP[mt] = (f32x4){0.f, 0.f, 0.f, 0.f};
        accQ[mt] = (f32x4){0.f, 0.f, 0.f, 0.f};
    }
#pragma unroll
    for (int s = 0; s < 2; ++s)
#pragma unroll
        for (int mt = 0; mt < 4; ++mt) {
            accP[mt] = __builtin_amdgcn_mfma_f32_16x16x32_bf16(aT[mt][s], bx[s], accP[mt], 0, 0, 0);
            accQ[mt] = __builtin_amdgcn_mfma_f32_16x16x32_bf16(aB[mt][s], bx[s], accQ[mt], 0, 0, 0);
        }

#pragma unroll
    for (int mt = 0; mt < 4; ++mt) {
        bf16x4 pv, qv;
#pragma unroll
        for (int r = 0; r < 4; ++r) { pv[r] = (__bf16)accP[mt][r]; qv[r] = (__bf16)accQ[mt][r]; }
        const size_t o = (size_t)node * 64 + mt * 16 + quad * 4;
        *(bf16x4*)(P + o) = pv;
        *(bf16x4*)(Q + o) = qv;
    }
}

// ---------------------------------------------------------------------------
// Edge stage 0: t0[e] = P[dst[e]] + Q[src[e]] (bf16 out), fused stats0.
// 2 threads per edge (32 cols each), grid-stride.
// ---------------------------------------------------------------------------
__global__ __launch_bounds__(256) void k_edge0(
    const __bf16* __restrict__ P, const __bf16* __restrict__ Q,
    const int* __restrict__ ei, __bf16* __restrict__ tb,
    float* __restrict__ sums)
{
    float sa[32], sq[32];
#pragma unroll
    for (int j = 0; j < 32; ++j) { sa[j] = 0.f; sq[j] = 0.f; }

    const int stride = gridDim.x * 256;
    for (int s = blockIdx.x * 256 + threadIdx.x; s < 2 * E_EDGES; s += stride) {
        const int e = s >> 1, half = s & 1;
        const int src = ei[e];
        const int dst = ei[E_EDGES + e];
        const bf16x8* pp = (const bf16x8*)(P + (size_t)dst * 64 + half * 32);
        const bf16x8* qp = (const bf16x8*)(Q + (size_t)src * 64 + half * 32);
        bf16x8 pf0 = pp[0], pf1 = pp[1], pf2 = pp[2], pf3 = pp[3];
        bf16x8 qf0 = qp[0], qf1 = qp[1], qf2 = qp[2], qf3 = qp[3];
        float v[32];
#pragma unroll
        for (int j = 0; j < 8; ++j) {
            v[j]      = (float)pf0[j] + (float)qf0[j];
            v[8 + j]  = (float)pf1[j] + (float)qf1[j];
            v[16 + j] = (float)pf2[j] + (float)qf2[j];
            v[24 + j] = (float)pf3[j] + (float)qf3[j];
        }
#pragma unroll
        for (int j = 0; j < 32; ++j) { sa[j] += v[j]; sq[j] = fmaf(v[j], v[j], sq[j]); }
        bf16x8 o[4];
#pragma unroll
        for (int q4 = 0; q4 < 4; ++q4)
#pragma unroll
            for (int j = 0; j < 8; ++j) o[q4][j] = (__bf16)v[q4 * 8 + j];
        bf16x8* to = (bf16x8*)(tb + (size_t)e * 64 + half * 32);
        to[0] = o[0]; to[1] = o[1]; to[2] = o[2]; to[3] = o[3];
    }

#pragma unroll
    for (int off = 2; off < 64; off <<= 1)
#pragma unroll
        for (int j = 0; j < 32; ++j) {
            sa[j] += __shfl_xor(sa[j], off);
            sq[j] += __shfl_xor(sq[j], off);
        }

    __shared__ float red[4][128];
    const int wave = threadIdx.x >> 6, lane = threadIdx.x & 63;
    if (lane < 2) {
        const int cbase = lane * 32;
#pragma unroll
        for (int j = 0; j < 32; ++j) {
            red[wave][cbase + j] = sa[j];
            red[wave][64 + cbase + j] = sq[j];
        }
    }
    __syncthreads();
    if (threadIdx.x < 128) {
        float v2 = red[0][threadIdx.x] + red[1][threadIdx.x] + red[2][threadIdx.x] + red[3][threadIdx.x];
        atomicAdd(&sums[threadIdx.x], v2);
    }
}

// ---------------------------------------------------------------------------
// Mid layer (swapped MFMA, grid-stride, prefetch): reads bf16 t rows,
// applies prev-BN affine+relu on load, writes OUTT (bf16 in place or fp32
// to tea). Fused stats epilogue. 1250 blocks x 4 waves, 10 groups/wave.
// ---------------------------------------------------------------------------
template <typename OUTT>
__global__ __launch_bounds__(256) void k_gemm_mid(
    const __bf16* __restrict__ tin, OUTT* __restrict__ tout,
    const __bf16* __restrict__ Wt, const float* __restrict__ sums_in,
    const float* __restrict__ g, const float* __restrict__ beta,
    float* __restrict__ sums_out)
{
    __shared__ float clds[128];
    __shared__ float sred[4][64], qred[4][64];
    if (threadIdx.x < 64) {
        const float inv_e = 1.f / (float)E_EDGES;
        const float mu = sums_in[threadIdx.x] * inv_e;
        const float var = sums_in[64 + threadIdx.x] * inv_e - mu * mu;
        const float a = g[threadIdx.x] * rsqrtf(var + BN_EPS);
        clds[threadIdx.x] = a;
        clds[64 + threadIdx.x] = beta[threadIdx.x] - mu * a;
    }
    __syncthreads();

    const int wave = threadIdx.x >> 6;
    const int lane = threadIdx.x & 63;
    const int quad = lane >> 4, lr = lane & 15;

    // BN coefs for this lane's k indices
    float ar[2][8], cr[2][8];
#pragma unroll
    for (int s = 0; s < 2; ++s)
#pragma unroll
        for (int j = 0; j < 8; ++j) {
            const int k = s * 32 + quad * 8 + j;
            ar[s][j] = clds[k];
            cr[s][j] = clds[64 + k];
        }

    // A fragments = weights (held in regs for whole kernel)
    bf16x8 af[4][2];
#pragma unroll
    for (int mt = 0; mt < 4; ++mt)
#pragma unroll
        for (int s = 0; s < 2; ++s)
            af[mt][s] = *(const bf16x8*)(Wt + (mt * 16 + lr) * 64 + s * 32 + quad * 8);

    float ss[16], sq[16];
#pragma unroll
    for (int i = 0; i < 16; ++i) { ss[i] = 0.f; sq[i] = 0.f; }

    const int WAVES = 1250 * 4;           // grid-wide waves
    int grp = blockIdx.x * 4 + wave;      // 10 iterations exactly
    size_t ebase = (size_t)(grp * 16 + lr) * 64;

    bf16x8 bcur0 = *(const bf16x8*)(tin + ebase + quad * 8);
    bf16x8 bcur1 = *(const bf16x8*)(tin + ebase + 32 + quad * 8);

#pragma unroll 1
    for (int it = 0; it < 10; ++it) {
        const int gn = grp + WAVES;
        const size_t enext = (size_t)(gn * 16 + lr) * 64;
        bf16x8 bn0, bn1;
        if (it < 9) {
            bn0 = *(const bf16x8*)(tin + enext + quad * 8);
            bn1 = *(const bf16x8*)(tin + enext + 32 + quad * 8);
        }

        // affine + relu -> bf16 B fragments
        bf16x8 bact0, bact1;
#pragma unroll
        for (int j = 0; j < 8; ++j) {
            bact0[j] = (__bf16)fmaxf(fmaf((float)bcur0[j], ar[0][j], cr[0][j]), 0.f);
            bact1[j] = (__bf16)fmaxf(fmaf((float)bcur1[j], ar[1][j], cr[1][j]), 0.f);
        }

        f32x4 acc[4];
#pragma unroll
        for (int mt = 0; mt < 4; ++mt) acc[mt] = (f32x4){0.f, 0.f, 0.f, 0.f};
#pragma unroll
        for (int mt = 0; mt < 4; ++mt) {
            acc[mt] = __builtin_amdgcn_mfma_f32_16x16x32_bf16(af[mt][0], bact0, acc[mt], 0, 0, 0);
            acc[mt] = __builtin_amdgcn_mfma_f32_16x16x32_bf16(af[mt][1], bact1, acc[mt], 0, 0, 0);
        }

        // store (lane holds 4 contiguous features of edge grp*16+lr) + stats
#pragma unroll
        for (int mt = 0; mt < 4; ++mt) {
            if constexpr (__is_same(OUTT, float)) {
                *(float4*)(tout + ebase + mt * 16 + quad * 4) =
                    make_float4(acc[mt][0], acc[mt][1], acc[mt][2], acc[mt][3]);
            } else {
                bf16x4 pv;
#pragma unroll
                for (int r = 0; r < 4; ++r) pv[r] = (__bf16)acc[mt][r];
                *(bf16x4*)(tout + ebase + mt * 16 + quad * 4) = pv;
            }
#pragma unroll
            for (int r = 0; r < 4; ++r) {
                const float v = acc[mt][r];
                ss[mt * 4 + r] += v;
                sq[mt * 4 + r] = fmaf(v, v, sq[mt * 4 + r]);
            }
        }

        bcur0 = bn0; bcur1 = bn1;
        grp = gn; ebase = enext;
    }

    // reduce stats over the 16 edges (lr bits), then block + atomic
#pragma unroll
    for (int i = 0; i < 16; ++i) {
        ss[i] += __shfl_xor(ss[i], 1); ss[i] += __shfl_xor(ss[i], 2);
        ss[i] += __shfl_xor(ss[i], 4); ss[i] += __shfl_xor(ss[i], 8);
        sq[i] += __shfl_xor(sq[i], 1); sq[i] += __shfl_xor(sq[i], 2);
        sq[i] += __shfl_xor(sq[i], 4); sq[i] += __shfl_xor(sq[i], 8);
    }
    if (lr == 0) {
#pragma unroll
        for (int mt = 0; mt < 4; ++mt)
#pragma unroll
            for (int r = 0; r < 4; ++r) {
                sred[wave][mt * 16 + quad * 4 + r] = ss[mt * 4 + r];
                qred[wave][mt * 16 + quad * 4 + r] = sq[mt * 4 + r];
            }
    }
    __syncthreads();
    if (threadIdx.x < 64) {
        const int c = threadIdx.x;
        atomicAdd(&sums_out[c], sred[0][c] + sred[1][c] + sred[2][c] + sred[3][c]);
        atomicAdd(&sums_out[64 + c], qred[0][c] + qred[1][c] + qred[2][c] + qred[3][c]);
    }
}

// ---------------------------------------------------------------------------
// Final: per node (one wave), 8 edges x 8 lanes: lane moves 32B contiguous
// (8 cols of one edge row). Affine+relu t2 (fp32, in place = edge_activations),
// accumulate, out = mean.
// ---------------------------------------------------------------------------
__global__ __launch_bounds__(256) void k_gather_apply(
    float* __restrict__ tea, const int* __restrict__ offsets,
    const int* __restrict__ counts, const int* __restrict__ eidx,
    const float* __restrict__ sums_in, const float* __restrict__ g,
    const float* __restrict__ beta, float* __restrict__ out)
{
    __shared__ float clds[128];
    if (threadIdx.x < 64) {
        const float inv_e = 1.f / (float)E_EDGES;
        const float mu = sums_in[threadIdx.x] * inv_e;
        const float var = sums_in[64 + threadIdx.x] * inv_e - mu * mu;
        const float a = g[threadIdx.x] * rsqrtf(var + BN_EPS);
        clds[threadIdx.x] = a;
        clds[64 + threadIdx.x] = beta[threadIdx.x] - mu * a;
    }
    __syncthreads();

    const int node = blockIdx.x * 4 + (threadIdx.x >> 6);
    const int lane = threadIdx.x & 63;
    const int es = lane >> 3;  // edge slot 0..7
    const int cc = lane & 7;   // col chunk (8 cols)

    float a[8], c[8];
#pragma unroll
    for (int j = 0; j < 8; ++j) { a[j] = clds[cc * 8 + j]; c[j] = clds[64 + cc * 8 + j]; }

    const int beg = offsets[node];
    const int cnt = counts[node];

    float acc8[8];
#pragma unroll
    for (int j = 0; j < 8; ++j) acc8[j] = 0.f;

    for (int i = 0; i < cnt; i += 8) {
        const int sub = i + es;
        if (sub < cnt) {
            const int e = eidx[beg + sub];
            float* rp = tea + (size_t)e * 64 + cc * 8;
            float4 v0 = *(float4*)rp;
            float4 v1 = *(float4*)(rp + 4);
            v0.x = fmaxf(fmaf(v0.x, a[0], c[0]), 0.f);
            v0.y = fmaxf(fmaf(v0.y, a[1], c[1]), 0.f);
            v0.z = fmaxf(fmaf(v0.z, a[2], c[2]), 0.f);
            v0.w = fmaxf(fmaf(v0.w, a[3], c[3]), 0.f);
            v1.x = fmaxf(fmaf(v1.x, a[4], c[4]), 0.f);
            v1.y = fmaxf(fmaf(v1.y, a[5], c[5]), 0.f);
            v1.z = fmaxf(fmaf(v1.z, a[6], c[6]), 0.f);
            v1.w = fmaxf(fmaf(v1.w, a[7], c[7]), 0.f);
            *(float4*)rp = v0;
            *(float4*)(rp + 4) = v1;
            acc8[0] += v0.x; acc8[1] += v0.y; acc8[2] += v0.z; acc8[3] += v0.w;
            acc8[4] += v1.x; acc8[5] += v1.y; acc8[6] += v1.z; acc8[7] += v1.w;
        }
    }

#pragma unroll
    for (int j = 0; j < 8; ++j) {
        acc8[j] += __shfl_xor(acc8[j], 8);
        acc8[j] += __shfl_xor(acc8[j], 16);
        acc8[j] += __shfl_xor(acc8[j], 32);
    }
    if (lane < 8) {  // es==0, cc==lane
        const float inv = 1.f / fmaxf((float)cnt, 1.f);
        float* op = out + (size_t)node * 64 + lane * 8;
        *(float4*)op = make_float4(acc8[0] * inv, acc8[1] * inv, acc8[2] * inv, acc8[3] * inv);
        *(float4*)(op + 4) = make_float4(acc8[4] * inv, acc8[5] * inv, acc8[6] * inv, acc8[7] * inv);
    }
}

extern "C" void kernel_launch(void* const* d_in, const int* in_sizes, int n_in,
                              void* d_out, int out_size, void* d_ws, size_t ws_size,
                              hipStream_t stream)
{
    (void)in_sizes; (void)n_in; (void)out_size; (void)ws_size;

    const float* x     = (const float*)d_in[0];
    const int*   ei    = (const int*)d_in[1];
    const float* W0    = (const float*)d_in[2];
    const float* g0    = (const float*)d_in[4];
    const float* beta0 = (const float*)d_in[5];
    const float* W1    = (const float*)d_in[6];
    const float* g1    = (const float*)d_in[8];
    const float* beta1 = (const float*)d_in[9];
    const float* W2    = (const float*)d_in[10];
    const float* g2    = (const float*)d_in[12];
    const float* beta2 = (const float*)d_in[13];

    float* out = (float*)d_out;            // [NN*64] node output
    float* tea = out + (size_t)NN * 64;    // [E*64] fp32 t2 == edge_activations

    char* ws = (char*)d_ws;
    int*    counts  = (int*)(ws + 0);             // 200000 B
    int*    offsets = (int*)(ws + 200704);
    int*    cursor  = (int*)(ws + 401408);
    float*  sums0   = (float*)(ws + 602112);      // 512 B each, contiguous
    float*  sums1   = (float*)(ws + 602624);
    float*  sums2   = (float*)(ws + 603136);
    __bf16* W0t_top = (__bf16*)(ws + 603648);     // 8192 B each
    __bf16* W0t_bot = (__bf16*)(ws + 611840);
    __bf16* Wt1     = (__bf16*)(ws + 620032);
    __bf16* Wt2     = (__bf16*)(ws + 628224);
    __bf16* P       = (__bf16*)(ws + 636928);     // 6.4 MB
    __bf16* Q       = (__bf16*)(ws + 7036928);    // 6.4 MB
    int*    eidx    = (int*)(ws + 13436928);      // 3.2 MB
    __bf16* tb      = (__bf16*)(ws + 16637952);   // 102.4 MB bf16 t0/t1

    hipMemsetAsync(counts, 0, NN * sizeof(int), stream);
    hipMemsetAsync(sums0, 0, 3 * 512, stream);

    const int GB = E_EDGES / 256;  // 3125

    k_prep<<<1, 256, 0, stream>>>(W0, W1, W2, W0t_top, W0t_bot, Wt1, Wt2);
    k_count<<<GB, 256, 0, stream>>>(ei, counts);
    k_scan<<<1, 256, 0, stream>>>(counts, offsets, cursor);
    k_fill<<<GB, 256, 0, stream>>>(ei, cursor, eidx);

    k_gemm_node<<<782, 256, 0, stream>>>(x, W0t_top, W0t_bot, P, Q);
    k_edge0<<<1563, 256, 0, stream>>>(P, Q, ei, tb, sums0);

    // BN0 inside mid1 (bf16 in-place), BN1 inside mid2 (fp32 -> tea),
    // BN2 inside gather.
    k_gemm_mid<__bf16><<<1250, 256, 0, stream>>>(tb, tb, Wt1, sums0, g0, beta0, sums1);
    k_gemm_mid<float><<<1250, 256, 0, stream>>>(tb, tea, Wt2, sums1, g1, beta1, sums2);

    k_gather_apply<<<NN / 4, 256, 0, stream>>>(tea, offsets, counts, eidx,
                                               sums2, g2, beta2, out);
}

// Round 5
// 670.456 us; speedup vs baseline: 5.7013x; 1.0554x over previous
//
#include <hip/hip_runtime.h>
#include <hip/hip_bf16.h>

#define E_EDGES 800000
#define NN 50000
#define BN_EPS 1e-5f

typedef __bf16 bf16x8 __attribute__((ext_vector_type(8)));
typedef __bf16 bf16x4 __attribute__((ext_vector_type(4)));
typedef float f32x4 __attribute__((ext_vector_type(4)));

// ---------------------------------------------------------------------------
// Prep: transpose + bf16-convert weights. Wt[n][k] = W[k][n].
// ---------------------------------------------------------------------------
__global__ void k_prep(const float* __restrict__ W0, const float* __restrict__ W1,
                       const float* __restrict__ W2, __bf16* __restrict__ W0t_top,
                       __bf16* __restrict__ W0t_bot, __bf16* __restrict__ Wt1,
                       __bf16* __restrict__ Wt2)
{
    for (int i = threadIdx.x; i < 4096; i += 256) {
        const int n = i >> 6, k = i & 63;
        W0t_top[n * 64 + k] = (__bf16)W0[k * 64 + n];
        W0t_bot[n * 64 + k] = (__bf16)W0[(64 + k) * 64 + n];
        Wt1[n * 64 + k] = (__bf16)W1[k * 64 + n];
        Wt2[n * 64 + k] = (__bf16)W2[k * 64 + n];
    }
}

// ---------------------------------------------------------------------------
// dst-degree histogram (int atomics, ~16 per address).
// ---------------------------------------------------------------------------
__global__ __launch_bounds__(256) void k_count(
    const int* __restrict__ ei, int* __restrict__ counts)
{
    const int e = blockIdx.x * 256 + threadIdx.x;
    atomicAdd(&counts[ei[E_EDGES + e]], 1);
}

// ---------------------------------------------------------------------------
// Exclusive scan of counts[NN] -> offsets, cursor.
// ---------------------------------------------------------------------------
__global__ __launch_bounds__(256) void k_scan(
    const int* __restrict__ counts, int* __restrict__ offsets,
    int* __restrict__ cursor)
{
    const int CHUNK = (NN + 255) / 256;  // 196
    const int t = threadIdx.x;
    const int beg = t * CHUNK;
    const int end = (beg + CHUNK < NN) ? beg + CHUNK : NN;
    int mysum = 0;
    for (int i = beg; i < end; ++i) mysum += counts[i];

    __shared__ int sd[256];
    sd[t] = mysum;
    __syncthreads();
    int run = mysum;
    for (int off = 1; off < 256; off <<= 1) {
        int v = (t >= off) ? sd[t - off] : 0;
        __syncthreads();
        sd[t] += v;
        __syncthreads();
    }
    int prefix = sd[t] - run;
    for (int i = beg; i < end; ++i) {
        offsets[i] = prefix;
        cursor[i] = prefix;
        prefix += counts[i];
    }
}

// ---------------------------------------------------------------------------
// CSR fill: pos = cursor[dst]++; record original edge id + src/dst per pos,
// so every downstream kernel reads its indices coalesced in position order.
// ---------------------------------------------------------------------------
__global__ __launch_bounds__(256) void k_fill(
    const int* __restrict__ ei, int* __restrict__ cursor,
    int* __restrict__ eidx, int* __restrict__ srcp, int* __restrict__ dstp)
{
    const int e = blockIdx.x * 256 + threadIdx.x;
    const int src = ei[e];
    const int dst = ei[E_EDGES + e];
    const int pos = atomicAdd(&cursor[dst], 1);
    eidx[pos] = e;
    srcp[pos] = src;
    dstp[pos] = dst;
}

// ---------------------------------------------------------------------------
// Node GEMM (swapped operands): P = x @ W0_top, Q = x @ W0_bot (bf16 out).
// ---------------------------------------------------------------------------
__global__ __launch_bounds__(256) void k_gemm_node(
    const float* __restrict__ x, const __bf16* __restrict__ W0t_top,
    const __bf16* __restrict__ W0t_bot, __bf16* __restrict__ P,
    __bf16* __restrict__ Q)
{
    const int wave = threadIdx.x >> 6;
    const int grp = blockIdx.x * 4 + wave;
    if (grp >= NN / 16) return;  // 3125 groups
    const int lane = threadIdx.x & 63;
    const int quad = lane >> 4, lr = lane & 15;

    bf16x8 aT[4][2], aB[4][2];
#pragma unroll
    for (int mt = 0; mt < 4; ++mt)
#pragma unroll
        for (int s = 0; s < 2; ++s) {
            const int off = (mt * 16 + lr) * 64 + s * 32 + quad * 8;
            aT[mt][s] = *(const bf16x8*)(W0t_top + off);
            aB[mt][s] = *(const bf16x8*)(W0t_bot + off);
        }

    const int node = grp * 16 + lr;
    bf16x8 bx[2];
#pragma unroll
    for (int s = 0; s < 2; ++s) {
        const float4* ap = (const float4*)(x + (size_t)node * 64 + s * 32 + quad * 8);
        const float4 v0 = ap[0], v1 = ap[1];
        bx[s][0] = (__bf16)v0.x; bx[s][1] = (__bf16)v0.y;
        bx[s][2] = (__bf16)v0.z; bx[s][3] = (__bf16)v0.w;
        bx[s][4] = (__bf16)v1.x; bx[s][5] = (__bf16)v1.y;
        bx[s][6] = (__bf16)v1.z; bx[s][7] = (__bf16)v1.w;
    }

    f32x4 accP[4], accQ[4];
#pragma unroll
    for (int mt = 0; mt < 4; ++mt) {
        accP[mt] = (f32x4){0.f, 0.f, 0.f, 0.f};
        accQ[mt] = (f32x4){0.f, 0.f, 0.f, 0.f};
    }
#pragma unroll
    for (int s = 0; s < 2; ++s)
#pragma unroll
        for (int mt = 0; mt < 4; ++mt) {
            accP[mt] = __builtin_amdgcn_mfma_f32_16x16x32_bf16(aT[mt][s], bx[s], accP[mt], 0, 0, 0);
            accQ[mt] = __builtin_amdgcn_mfma_f32_16x16x32_bf16(aB[mt][s], bx[s], accQ[mt], 0, 0, 0);
        }

#pragma unroll
    for (int mt = 0; mt < 4; ++mt) {
        bf16x4 pv, qv;
#pragma unroll
        for (int r = 0; r < 4; ++r) { pv[r] = (__bf16)accP[mt][r]; qv[r] = (__bf16)accQ[mt][r]; }
        const size_t o = (size_t)node * 64 + mt * 16 + quad * 4;
        *(bf16x4*)(P + o) = pv;
        *(bf16x4*)(Q + o) = qv;
    }
}

// ---------------------------------------------------------------------------
// Edge stage 0 (CSR-position order): tb[p] = P[dstp[p]] + Q[srcp[p]] (bf16),
// fused stats0. dstp is sorted -> P gathers are cache-local.
// 2 threads per position (32 cols each), grid-stride.
// ---------------------------------------------------------------------------
__global__ __launch_bounds__(256) void k_edge0(
    const __bf16* __restrict__ P, const __bf16* __restrict__ Q,
    const int* __restrict__ srcp, const int* __restrict__ dstp,
    __bf16* __restrict__ tb, float* __restrict__ sums)
{
    float sa[32], sq[32];
#pragma unroll
    for (int j = 0; j < 32; ++j) { sa[j] = 0.f; sq[j] = 0.f; }

    const int stride = gridDim.x * 256;
    for (int s = blockIdx.x * 256 + threadIdx.x; s < 2 * E_EDGES; s += stride) {
        const int p = s >> 1, half = s & 1;
        const int src = srcp[p];
        const int dst = dstp[p];
        const bf16x8* pp = (const bf16x8*)(P + (size_t)dst * 64 + half * 32);
        const bf16x8* qp = (const bf16x8*)(Q + (size_t)src * 64 + half * 32);
        bf16x8 pf0 = pp[0], pf1 = pp[1], pf2 = pp[2], pf3 = pp[3];
        bf16x8 qf0 = qp[0], qf1 = qp[1], qf2 = qp[2], qf3 = qp[3];
        float v[32];
#pragma unroll
        for (int j = 0; j < 8; ++j) {
            v[j]      = (float)pf0[j] + (float)qf0[j];
            v[8 + j]  = (float)pf1[j] + (float)qf1[j];
            v[16 + j] = (float)pf2[j] + (float)qf2[j];
            v[24 + j] = (float)pf3[j] + (float)qf3[j];
        }
#pragma unroll
        for (int j = 0; j < 32; ++j) { sa[j] += v[j]; sq[j] = fmaf(v[j], v[j], sq[j]); }
        bf16x8 o[4];
#pragma unroll
        for (int q4 = 0; q4 < 4; ++q4)
#pragma unroll
            for (int j = 0; j < 8; ++j) o[q4][j] = (__bf16)v[q4 * 8 + j];
        bf16x8* to = (bf16x8*)(tb + (size_t)p * 64 + half * 32);
        to[0] = o[0]; to[1] = o[1]; to[2] = o[2]; to[3] = o[3];
    }

#pragma unroll
    for (int off = 2; off < 64; off <<= 1)
#pragma unroll
        for (int j = 0; j < 32; ++j) {
            sa[j] += __shfl_xor(sa[j], off);
            sq[j] += __shfl_xor(sq[j], off);
        }

    __shared__ float red[4][128];
    const int wave = threadIdx.x >> 6, lane = threadIdx.x & 63;
    if (lane < 2) {
        const int cbase = lane * 32;
#pragma unroll
        for (int j = 0; j < 32; ++j) {
            red[wave][cbase + j] = sa[j];
            red[wave][64 + cbase + j] = sq[j];
        }
    }
    __syncthreads();
    if (threadIdx.x < 128) {
        float v2 = red[0][threadIdx.x] + red[1][threadIdx.x] + red[2][threadIdx.x] + red[3][threadIdx.x];
        atomicAdd(&sums[threadIdx.x], v2);
    }
}

// ---------------------------------------------------------------------------
// Mid layer (swapped MFMA, grid-stride, prefetch): bf16 in -> bf16 out,
// in place; prev-BN affine+relu on load; fused stats epilogue.
// 1250 blocks x 4 waves, 10 groups/wave.
// ---------------------------------------------------------------------------
__global__ __launch_bounds__(256) void k_gemm_mid(
    const __bf16* __restrict__ tin, __bf16* __restrict__ tout,
    const __bf16* __restrict__ Wt, const float* __restrict__ sums_in,
    const float* __restrict__ g, const float* __restrict__ beta,
    float* __restrict__ sums_out)
{
    __shared__ float clds[128];
    __shared__ float sred[4][64], qred[4][64];
    if (threadIdx.x < 64) {
        const float inv_e = 1.f / (float)E_EDGES;
        const float mu = sums_in[threadIdx.x] * inv_e;
        const float var = sums_in[64 + threadIdx.x] * inv_e - mu * mu;
        const float a = g[threadIdx.x] * rsqrtf(var + BN_EPS);
        clds[threadIdx.x] = a;
        clds[64 + threadIdx.x] = beta[threadIdx.x] - mu * a;
    }
    __syncthreads();

    const int wave = threadIdx.x >> 6;
    const int lane = threadIdx.x & 63;
    const int quad = lane >> 4, lr = lane & 15;

    float ar[2][8], cr[2][8];
#pragma unroll
    for (int s = 0; s < 2; ++s)
#pragma unroll
        for (int j = 0; j < 8; ++j) {
            const int k = s * 32 + quad * 8 + j;
            ar[s][j] = clds[k];
            cr[s][j] = clds[64 + k];
        }

    bf16x8 af[4][2];
#pragma unroll
    for (int mt = 0; mt < 4; ++mt)
#pragma unroll
        for (int s = 0; s < 2; ++s)
            af[mt][s] = *(const bf16x8*)(Wt + (mt * 16 + lr) * 64 + s * 32 + quad * 8);

    float ss[16], sq[16];
#pragma unroll
    for (int i = 0; i < 16; ++i) { ss[i] = 0.f; sq[i] = 0.f; }

    const int WAVES = 1250 * 4;
    int grp = blockIdx.x * 4 + wave;      // 10 iterations exactly
    size_t ebase = (size_t)(grp * 16 + lr) * 64;

    bf16x8 bcur0 = *(const bf16x8*)(tin + ebase + quad * 8);
    bf16x8 bcur1 = *(const bf16x8*)(tin + ebase + 32 + quad * 8);

#pragma unroll 1
    for (int it = 0; it < 10; ++it) {
        const int gn = grp + WAVES;
        const size_t enext = (size_t)(gn * 16 + lr) * 64;
        bf16x8 bn0, bn1;
        if (it < 9) {
            bn0 = *(const bf16x8*)(tin + enext + quad * 8);
            bn1 = *(const bf16x8*)(tin + enext + 32 + quad * 8);
        }

        bf16x8 bact0, bact1;
#pragma unroll
        for (int j = 0; j < 8; ++j) {
            bact0[j] = (__bf16)fmaxf(fmaf((float)bcur0[j], ar[0][j], cr[0][j]), 0.f);
            bact1[j] = (__bf16)fmaxf(fmaf((float)bcur1[j], ar[1][j], cr[1][j]), 0.f);
        }

        f32x4 acc[4];
#pragma unroll
        for (int mt = 0; mt < 4; ++mt) acc[mt] = (f32x4){0.f, 0.f, 0.f, 0.f};
#pragma unroll
        for (int mt = 0; mt < 4; ++mt) {
            acc[mt] = __builtin_amdgcn_mfma_f32_16x16x32_bf16(af[mt][0], bact0, acc[mt], 0, 0, 0);
            acc[mt] = __builtin_amdgcn_mfma_f32_16x16x32_bf16(af[mt][1], bact1, acc[mt], 0, 0, 0);
        }

#pragma unroll
        for (int mt = 0; mt < 4; ++mt) {
            bf16x4 pv;
#pragma unroll
            for (int r = 0; r < 4; ++r) pv[r] = (__bf16)acc[mt][r];
            *(bf16x4*)(tout + ebase + mt * 16 + quad * 4) = pv;
#pragma unroll
            for (int r = 0; r < 4; ++r) {
                const float v = acc[mt][r];
                ss[mt * 4 + r] += v;
                sq[mt * 4 + r] = fmaf(v, v, sq[mt * 4 + r]);
            }
        }

        bcur0 = bn0; bcur1 = bn1;
        grp = gn; ebase = enext;
    }

#pragma unroll
    for (int i = 0; i < 16; ++i) {
        ss[i] += __shfl_xor(ss[i], 1); ss[i] += __shfl_xor(ss[i], 2);
        ss[i] += __shfl_xor(ss[i], 4); ss[i] += __shfl_xor(ss[i], 8);
        sq[i] += __shfl_xor(sq[i], 1); sq[i] += __shfl_xor(sq[i], 2);
        sq[i] += __shfl_xor(sq[i], 4); sq[i] += __shfl_xor(sq[i], 8);
    }
    if (lr == 0) {
#pragma unroll
        for (int mt = 0; mt < 4; ++mt)
#pragma unroll
            for (int r = 0; r < 4; ++r) {
                sred[wave][mt * 16 + quad * 4 + r] = ss[mt * 4 + r];
                qred[wave][mt * 16 + quad * 4 + r] = sq[mt * 4 + r];
            }
    }
    __syncthreads();
    if (threadIdx.x < 64) {
        const int c = threadIdx.x;
        atomicAdd(&sums_out[c], sred[0][c] + sred[1][c] + sred[2][c] + sred[3][c]);
        atomicAdd(&sums_out[64 + c], qred[0][c] + qred[1][c] + qred[2][c] + qred[3][c]);
    }
}

// ---------------------------------------------------------------------------
// Final: per node (one wave), node's rows are CONTIGUOUS in tb (CSR order).
// 8 rows x 8 lanes per step: lane reads 16B bf16 (coalesced 1KB/wave),
// applies BN2+relu, scatter-writes the fp32 edge_activations row to its
// original edge slot (full-line writes), reduces, writes mean.
// ---------------------------------------------------------------------------
__global__ __launch_bounds__(256) void k_gather_apply(
    const __bf16* __restrict__ tb, const int* __restrict__ offsets,
    const int* __restrict__ counts, const int* __restrict__ eidx,
    const float* __restrict__ sums_in, const float* __restrict__ g,
    const float* __restrict__ beta, float* __restrict__ tea,
    float* __restrict__ out)
{
    __shared__ float clds[128];
    if (threadIdx.x < 64) {
        const float inv_e = 1.f / (float)E_EDGES;
        const float mu = sums_in[threadIdx.x] * inv_e;
        const float var = sums_in[64 + threadIdx.x] * inv_e - mu * mu;
        const float a = g[threadIdx.x] * rsqrtf(var + BN_EPS);
        clds[threadIdx.x] = a;
        clds[64 + threadIdx.x] = beta[threadIdx.x] - mu * a;
    }
    __syncthreads();

    const int node = blockIdx.x * 4 + (threadIdx.x >> 6);
    const int lane = threadIdx.x & 63;
    const int es = lane >> 3;  // row slot 0..7
    const int cc = lane & 7;   // col chunk (8 cols)

    float a[8], c[8];
#pragma unroll
    for (int j = 0; j < 8; ++j) { a[j] = clds[cc * 8 + j]; c[j] = clds[64 + cc * 8 + j]; }

    const int beg = offsets[node];
    const int cnt = counts[node];

    float acc8[8];
#pragma unroll
    for (int j = 0; j < 8; ++j) acc8[j] = 0.f;

    for (int i = 0; i < cnt; i += 8) {
        const int sub = i + es;
        if (sub < cnt) {
            const int p = beg + sub;
            const bf16x8 v = *(const bf16x8*)(tb + (size_t)p * 64 + cc * 8);
            const int e = eidx[p];
            float vv[8];
#pragma unroll
            for (int j = 0; j < 8; ++j)
                vv[j] = fmaxf(fmaf((float)v[j], a[j], c[j]), 0.f);
            float* rp = tea + (size_t)e * 64 + cc * 8;
            *(float4*)rp = make_float4(vv[0], vv[1], vv[2], vv[3]);
            *(float4*)(rp + 4) = make_float4(vv[4], vv[5], vv[6], vv[7]);
#pragma unroll
            for (int j = 0; j < 8; ++j) acc8[j] += vv[j];
        }
    }

#pragma unroll
    for (int j = 0; j < 8; ++j) {
        acc8[j] += __shfl_xor(acc8[j], 8);
        acc8[j] += __shfl_xor(acc8[j], 16);
        acc8[j] += __shfl_xor(acc8[j], 32);
    }
    if (lane < 8) {  // es==0, cc==lane
        const float inv = 1.f / fmaxf((float)cnt, 1.f);
        float* op = out + (size_t)node * 64 + lane * 8;
        *(float4*)op = make_float4(acc8[0] * inv, acc8[1] * inv, acc8[2] * inv, acc8[3] * inv);
        *(float4*)(op + 4) = make_float4(acc8[4] * inv, acc8[5] * inv, acc8[6] * inv, acc8[7] * inv);
    }
}

extern "C" void kernel_launch(void* const* d_in, const int* in_sizes, int n_in,
                              void* d_out, int out_size, void* d_ws, size_t ws_size,
                              hipStream_t stream)
{
    (void)in_sizes; (void)n_in; (void)out_size; (void)ws_size;

    const float* x     = (const float*)d_in[0];
    const int*   ei    = (const int*)d_in[1];
    const float* W0    = (const float*)d_in[2];
    const float* g0    = (const float*)d_in[4];
    const float* beta0 = (const float*)d_in[5];
    const float* W1    = (const float*)d_in[6];
    const float* g1    = (const float*)d_in[8];
    const float* beta1 = (const float*)d_in[9];
    const float* W2    = (const float*)d_in[10];
    const float* g2    = (const float*)d_in[12];
    const float* beta2 = (const float*)d_in[13];

    float* out = (float*)d_out;            // [NN*64] node output
    float* tea = out + (size_t)NN * 64;    // [E*64] fp32 edge_activations

    char* ws = (char*)d_ws;
    int*    counts  = (int*)(ws + 0);             // 200000 B
    int*    offsets = (int*)(ws + 200704);
    int*    cursor  = (int*)(ws + 401408);
    float*  sums0   = (float*)(ws + 602112);      // 512 B each, contiguous
    float*  sums1   = (float*)(ws + 602624);
    float*  sums2   = (float*)(ws + 603136);
    __bf16* W0t_top = (__bf16*)(ws + 603648);     // 8192 B each
    __bf16* W0t_bot = (__bf16*)(ws + 611840);
    __bf16* Wt1     = (__bf16*)(ws + 620032);
    __bf16* Wt2     = (__bf16*)(ws + 628224);
    __bf16* P       = (__bf16*)(ws + 636928);     // 6.4 MB
    __bf16* Q       = (__bf16*)(ws + 7036928);    // 6.4 MB
    int*    eidx    = (int*)(ws + 13436928);      // 3.2 MB
    int*    srcp    = (int*)(ws + 16636928);      // 3.2 MB
    int*    dstp    = (int*)(ws + 19836928);      // 3.2 MB
    __bf16* tb      = (__bf16*)(ws + 23036928);   // 102.4 MB bf16 t (CSR order)

    hipMemsetAsync(counts, 0, NN * sizeof(int), stream);
    hipMemsetAsync(sums0, 0, 3 * 512, stream);

    const int GB = E_EDGES / 256;  // 3125

    k_prep<<<1, 256, 0, stream>>>(W0, W1, W2, W0t_top, W0t_bot, Wt1, Wt2);
    k_count<<<GB, 256, 0, stream>>>(ei, counts);
    k_scan<<<1, 256, 0, stream>>>(counts, offsets, cursor);
    k_fill<<<GB, 256, 0, stream>>>(ei, cursor, eidx, srcp, dstp);

    k_gemm_node<<<782, 256, 0, stream>>>(x, W0t_top, W0t_bot, P, Q);
    k_edge0<<<1563, 256, 0, stream>>>(P, Q, srcp, dstp, tb, sums0);

    // BN0 inside mid1, BN1 inside mid2 (both bf16 in place), BN2 in gather.
    k_gemm_mid<<<1250, 256, 0, stream>>>(tb, tb, Wt1, sums0, g0, beta0, sums1);
    k_gemm_mid<<<1250, 256, 0, stream>>>(tb, tb, Wt2, sums1, g1, beta1, sums2);

    k_gather_apply<<<NN / 4, 256, 0, stream>>>(tb, offsets, counts, eidx,
                                               sums2, g2, beta2, tea, out);
}